// Round 6
// baseline (499.134 us; speedup 1.0000x reference)
//
#include <hip/hip_runtime.h>
#include <hip/hip_bf16.h>
#include <cstdint>

// Problem constants
#define B_ 4
#define N_ 2048
#define C_ 768
#define H_ 12
#define D_ 64
// SCALE = D^-0.5 = 0.125; folded exp2 scale = 0.125 * log2(e)
#define QSCALE 0.18033688011112042f

typedef __bf16 bf16x8 __attribute__((ext_vector_type(8)));
typedef float f32x4 __attribute__((ext_vector_type(4)));

// RNE float -> bf16 bits (branchless; inputs are finite)
__device__ __forceinline__ unsigned f2bs(float x) {
  unsigned u = __builtin_bit_cast(unsigned, x);
  unsigned r = (u + 0x7fffu + ((u >> 16) & 1u)) >> 16;
  return r;
}

__device__ __forceinline__ bf16x8 ldb8(const unsigned short* p) {
  return __builtin_bit_cast(bf16x8, *(const uint4*)p);
}

__device__ __forceinline__ f32x4 mfma16(bf16x8 a, bf16x8 b, f32x4 c) {
  return __builtin_amdgcn_mfma_f32_16x16x32_bf16(a, b, c, 0, 0, 0);
}

// ---------------- x conversion: 3 x (B*N*C) f32 -> bf16 ----------------
__global__ void convx_kernel(const float* __restrict__ s0, const float* __restrict__ s1,
                             const float* __restrict__ s2,
                             unsigned short* __restrict__ d0, unsigned short* __restrict__ d1,
                             unsigned short* __restrict__ d2) {
  const float* s; unsigned short* d;
  switch (blockIdx.y) {
    case 0: s = s0; d = d0; break;
    case 1: s = s1; d = d1; break;
    default: s = s2; d = d2; break;
  }
  int i = (blockIdx.x * 256 + threadIdx.x) * 4;   // grid.x=6144 covers 6291456 exactly
  float4 v = *(const float4*)(s + i);
  ushort4 h;
  h.x = (unsigned short)f2bs(v.x); h.y = (unsigned short)f2bs(v.y);
  h.z = (unsigned short)f2bs(v.z); h.w = (unsigned short)f2bs(v.w);
  *(ushort4*)(d + i) = h;
}

// ---------------- weight conversion: 4 x (768x768) f32 -> bf16 ----------------
__global__ void convw_kernel(const float* __restrict__ s0, const float* __restrict__ s1,
                             const float* __restrict__ s2, const float* __restrict__ s3,
                             unsigned short* __restrict__ d0, unsigned short* __restrict__ d1,
                             unsigned short* __restrict__ d2, unsigned short* __restrict__ d3) {
  const float* s; unsigned short* d;
  switch (blockIdx.y) {
    case 0: s = s0; d = d0; break;
    case 1: s = s1; d = d1; break;
    case 2: s = s2; d = d2; break;
    default: s = s3; d = d3; break;
  }
  int i = (blockIdx.x * 256 + threadIdx.x) * 4;   // grid.x=576 -> 589824 exactly
  float4 v = *(const float4*)(s + i);
  ushort4 h;
  h.x = (unsigned short)f2bs(v.x); h.y = (unsigned short)f2bs(v.y);
  h.z = (unsigned short)f2bs(v.z); h.w = (unsigned short)f2bs(v.w);
  *(ushort4*)(d + i) = h;
}

// ---------------- uc[b,n] = mean over C of x_u ----------------
__global__ void uc_kernel(const float* __restrict__ xu, float* __restrict__ uc) {
  int w = threadIdx.x >> 6, lane = threadIdx.x & 63;
  int row = blockIdx.x * 4 + w;                   // grid 2048 -> 8192 rows
  const float* p = xu + (size_t)row * C_;
  float s = 0.f;
#pragma unroll
  for (int i = 0; i < 3; ++i) {
    float4 v = *(const float4*)(p + (i * 64 + lane) * 4);
    s += v.x + v.y + v.z + v.w;
  }
#pragma unroll
  for (int off = 1; off < 64; off <<= 1) s += __shfl_xor(s, off);
  if (lane == 0) uc[row] = s * (1.f / 768.f);
}

// ---------------- GEMM mainloop (128x128 tile, BK=64, REGISTER-PREFETCH staging) ----
// A [8192 x 768] bf16 row-major, W [768 x 768] bf16 row-major (NT gemm).
// LDS layout: two 32-col panels per BK=64 tile: panel kk at offset kk*4096 shorts,
// [row][32] row-major. Granule g = s*256+tid maps to LDS shorts [g*8 .. g*8+7],
// source row=(g>>2)&127, col = ((g>>9)<<5)|((g&3)<<3).
// Pipeline: regs hold tile kt; barrier; regs->LDS; barrier; issue loads kt+64;
// compute on LDS. Global latency overlaps compute instead of stalling barriers.
__device__ __forceinline__ void gemm_mainloop(
    const unsigned short* __restrict__ A, const unsigned short* __restrict__ W,
    int m0, int n0, unsigned short* Al, unsigned short* Bl,
    int tid, int wm, int wn, int quad, int id15, f32x4 (*acc)[4]) {
  const unsigned short* ap[4];
  const unsigned short* bp[4];
#pragma unroll
  for (int s = 0; s < 4; ++s) {
    int g = s * 256 + tid;
    int row = (g >> 2) & 127;
    int col = ((g >> 9) << 5) | ((g & 3) << 3);
    ap[s] = A + (size_t)(m0 + row) * C_ + col;
    bp[s] = W + (size_t)(n0 + row) * C_ + col;
  }

  uint4 ra[4], rb[4];
#pragma unroll
  for (int s = 0; s < 4; ++s) {
    ra[s] = *(const uint4*)(ap[s]);
    rb[s] = *(const uint4*)(bp[s]);
  }

  for (int kt = 0; kt < C_; kt += 64) {
    __syncthreads();                      // all waves done reading LDS (prev tile)
#pragma unroll
    for (int s = 0; s < 4; ++s) {
      *(uint4*)&Al[(s * 256 + tid) * 8] = ra[s];
      *(uint4*)&Bl[(s * 256 + tid) * 8] = rb[s];
    }
    __syncthreads();

    if (kt + 64 < C_) {                   // issue next tile's loads; wait lands next iter
#pragma unroll
      for (int s = 0; s < 4; ++s) {
        ra[s] = *(const uint4*)(ap[s] + kt + 64);
        rb[s] = *(const uint4*)(bp[s] + kt + 64);
      }
    }

#pragma unroll
    for (int kk = 0; kk < 2; ++kk) {
      bf16x8 af[4], bfr[4];
#pragma unroll
      for (int i = 0; i < 4; ++i)
        af[i]  = ldb8(&Al[kk * 4096 + (wm + i * 16 + id15) * 32 + quad * 8]);
#pragma unroll
      for (int j = 0; j < 4; ++j)
        bfr[j] = ldb8(&Bl[kk * 4096 + (wn + j * 16 + id15) * 32 + quad * 8]);
#pragma unroll
      for (int i = 0; i < 4; ++i)
#pragma unroll
        for (int j = 0; j < 4; ++j)
          acc[i][j] = mfma16(af[i], bfr[j], acc[i][j]);
    }
  }
}

// ---------------- fused QKV projection ----------------
// z=0: Q = x_q@Wq^T * QSCALE*uc (log2e folded), bf16 [B*N, C]
// z=1: K = x_k@Wk^T,            bf16 [B*N, C]
// z=2: V^T[b*C+o][n] = x_v@Wv^T bf16 transposed
__global__ __launch_bounds__(256, 3) void gemm_qkv(
    const unsigned short* __restrict__ xq, const unsigned short* __restrict__ xk,
    const unsigned short* __restrict__ xv,
    const unsigned short* __restrict__ wq, const unsigned short* __restrict__ wk,
    const unsigned short* __restrict__ wv,
    unsigned short* __restrict__ oq, unsigned short* __restrict__ ok,
    unsigned short* __restrict__ ov, const float* __restrict__ uc) {
  __shared__ __align__(16) unsigned short Al[128 * 64];
  __shared__ __align__(16) unsigned short Bl[128 * 64];
  const int tid = threadIdx.x;
  const int w = tid >> 6, lane = tid & 63, quad = lane >> 4, id15 = lane & 15;
  const int wm = (w >> 1) << 6, wn = (w & 1) << 6;
  const int m0 = blockIdx.y << 7, n0 = blockIdx.x << 7;
  const int z = blockIdx.z;

  const unsigned short* A = (z == 0) ? xq : (z == 1) ? xk : xv;
  const unsigned short* W = (z == 0) ? wq : (z == 1) ? wk : wv;

  f32x4 acc[4][4] = {};
  gemm_mainloop(A, W, m0, n0, Al, Bl, tid, wm, wn, quad, id15, acc);

#pragma unroll
  for (int i = 0; i < 4; ++i) {
#pragma unroll
    for (int j = 0; j < 4; ++j) {
#pragma unroll
      for (int r = 0; r < 4; ++r) {
        int gm = m0 + wm + i * 16 + quad * 4 + r;   // global row (b*N + n)
        int gn = n0 + wn + j * 16 + id15;           // global out channel
        float v = acc[i][j][r];
        if (z == 0) {
          v *= QSCALE * uc[gm];
          oq[(size_t)gm * C_ + gn] = (unsigned short)f2bs(v);
        } else if (z == 1) {
          ok[(size_t)gm * C_ + gn] = (unsigned short)f2bs(v);
        } else {
          int b = gm >> 11, n = gm & (N_ - 1);
          ov[(size_t)(b * C_ + gn) * N_ + n] = (unsigned short)f2bs(v);
        }
      }
    }
  }
}

// ---------------- output projection: out = ao@Wp^T + bp, f32 ----------------
__global__ __launch_bounds__(256, 3) void gemm_out(
    const unsigned short* __restrict__ ao, const unsigned short* __restrict__ wp,
    float* __restrict__ out, const float* __restrict__ bias) {
  __shared__ __align__(16) unsigned short Al[128 * 64];
  __shared__ __align__(16) unsigned short Bl[128 * 64];
  const int tid = threadIdx.x;
  const int w = tid >> 6, lane = tid & 63, quad = lane >> 4, id15 = lane & 15;
  const int wm = (w >> 1) << 6, wn = (w & 1) << 6;
  const int m0 = blockIdx.y << 7, n0 = blockIdx.x << 7;

  f32x4 acc[4][4] = {};
  gemm_mainloop(ao, wp, m0, n0, Al, Bl, tid, wm, wn, quad, id15, acc);

#pragma unroll
  for (int i = 0; i < 4; ++i) {
#pragma unroll
    for (int j = 0; j < 4; ++j) {
#pragma unroll
      for (int r = 0; r < 4; ++r) {
        int gm = m0 + wm + i * 16 + quad * 4 + r;
        int gn = n0 + wn + j * 16 + id15;
        out[(size_t)gm * C_ + gn] = acc[i][j][r] + bias[gn];
      }
    }
  }
}

// ---------------- Flash attention (S^T, exp2, MFMA-lsum, register prefetch) --------
// Q: [B,N,C] bf16 (pre-scaled by QSCALE*uc, log2e folded); K: [B,N,C] bf16;
// Vt: [B*C, N] bf16. O: [B,N,C] bf16.
// Grid: (N/128, B*H), block 256 (4 waves x 32 q-rows). K-chunks of 64.
#define KSTR 72   // K/V LDS row stride (shorts): 144 B, 16B-aligned rows
#define PSTR 72
__global__ __launch_bounds__(256, 3) void attn_kernel(
    const unsigned short* __restrict__ Q, const unsigned short* __restrict__ Kk,
    const unsigned short* __restrict__ Vt, unsigned short* __restrict__ O) {
  __shared__ __align__(16) unsigned short Kl[64 * KSTR];
  __shared__ __align__(16) unsigned short Vl[64 * KSTR];
  __shared__ __align__(16) unsigned short Pl[8][16 * PSTR];   // per (wave, rg)

  const int tid = threadIdx.x;
  const int w = tid >> 6, lane = tid & 63, quad = lane >> 4, id15 = lane & 15;
  const int bh = blockIdx.y;
  const int b = bh / H_, h = bh % H_;
  const int q0 = blockIdx.x * 128 + w * 32;

  bf16x8 qf[2][2];
#pragma unroll
  for (int rg = 0; rg < 2; ++rg)
#pragma unroll
    for (int kb = 0; kb < 2; ++kb)
      qf[rg][kb] = ldb8(Q + (size_t)(b * N_ + q0 + rg * 16 + id15) * C_ + h * 64 + kb * 32 + quad * 8);

  const uint4 onesu = {0x3F803F80u, 0x3F803F80u, 0x3F803F80u, 0x3F803F80u};
  const bf16x8 onesf = __builtin_bit_cast(bf16x8, onesu);

  f32x4 oacc[2][4] = {};
  f32x4 lacc[2] = {};

  const size_t kbase = (size_t)(b * N_) * C_ + h * 64;
  const size_t vbase = (size_t)(b * C_ + h * 64) * N_;
  const int srow0 = tid >> 3, srow1 = (256 + tid) >> 3;
  const int sseg0 = (tid & 7) << 3;

  const unsigned short* kp0 = Kk + kbase + (size_t)srow0 * C_ + sseg0;
  const unsigned short* kp1 = Kk + kbase + (size_t)srow1 * C_ + sseg0;
  const unsigned short* vp0 = Vt + vbase + (size_t)srow0 * N_ + sseg0;
  const unsigned short* vp1 = Vt + vbase + (size_t)srow1 * N_ + sseg0;

  unsigned short* Plw0 = &Pl[w * 2 + 0][0];
  unsigned short* Plw1 = &Pl[w * 2 + 1][0];

  // prologue: prefetch chunk 0 into regs
  uint4 rk0 = *(const uint4*)(kp0);
  uint4 rk1 = *(const uint4*)(kp1);
  uint4 rv0 = *(const uint4*)(vp0);
  uint4 rv1 = *(const uint4*)(vp1);

  for (int kc = 0; kc < N_; kc += 64) {
    __syncthreads();                      // waves done reading K/V LDS (prev chunk)
    *(uint4*)&Kl[srow0 * KSTR + sseg0] = rk0;
    *(uint4*)&Kl[srow1 * KSTR + sseg0] = rk1;
    *(uint4*)&Vl[srow0 * KSTR + sseg0] = rv0;
    *(uint4*)&Vl[srow1 * KSTR + sseg0] = rv1;
    __syncthreads();

    if (kc + 64 < N_) {                   // issue next chunk's loads now; wait next iter
      rk0 = *(const uint4*)(kp0 + (size_t)(kc + 64) * C_);
      rk1 = *(const uint4*)(kp1 + (size_t)(kc + 64) * C_);
      rv0 = *(const uint4*)(vp0 + (kc + 64));
      rv1 = *(const uint4*)(vp1 + (kc + 64));
    }

    // Phase 1: S^T for both row-groups, K-frags shared
    f32x4 sA[4], sB[4];
#pragma unroll
    for (int cb = 0; cb < 4; ++cb) {
      f32x4 a = {}, c = {};
#pragma unroll
      for (int kb = 0; kb < 2; ++kb) {
        bf16x8 kf = ldb8(&Kl[(cb * 16 + id15) * KSTR + kb * 32 + quad * 8]);
        a = mfma16(kf, qf[0][kb], a);
        c = mfma16(kf, qf[1][kb], c);
      }
      sA[cb] = a; sB[cb] = c;
    }

    // Phase 2: exp2 + truncate-pack (1 v_perm per pair) + vectorized P write
#pragma unroll
    for (int rg = 0; rg < 2; ++rg) {
      f32x4* s4 = (rg == 0) ? sA : sB;
      unsigned short* Plw = (rg == 0) ? Plw0 : Plw1;
#pragma unroll
      for (int cb = 0; cb < 4; ++cb) {
        unsigned p0 = __builtin_bit_cast(unsigned, exp2f(s4[cb][0]));
        unsigned p1 = __builtin_bit_cast(unsigned, exp2f(s4[cb][1]));
        unsigned p2 = __builtin_bit_cast(unsigned, exp2f(s4[cb][2]));
        unsigned p3 = __builtin_bit_cast(unsigned, exp2f(s4[cb][3]));
        uint2 u;
        u.x = __builtin_amdgcn_perm(p1, p0, 0x07060302u);
        u.y = __builtin_amdgcn_perm(p3, p2, 0x07060302u);
        *(uint2*)&Plw[id15 * PSTR + cb * 16 + quad * 4] = u;
      }
    }

    // Phase 3: P fragments (A-operand)
    bf16x8 pf[2][2];
#pragma unroll
    for (int kb = 0; kb < 2; ++kb) {
      pf[0][kb] = ldb8(&Plw0[id15 * PSTR + kb * 32 + quad * 8]);
      pf[1][kb] = ldb8(&Plw1[id15 * PSTR + kb * 32 + quad * 8]);
    }

    // Phase 4: PV + ones-MFMA row-sum (matrix pipe), V-frags shared
#pragma unroll
    for (int kb = 0; kb < 2; ++kb) {
      lacc[0] = mfma16(pf[0][kb], onesf, lacc[0]);
      lacc[1] = mfma16(pf[1][kb], onesf, lacc[1]);
    }
#pragma unroll
    for (int db = 0; db < 4; ++db) {
#pragma unroll
      for (int kb = 0; kb < 2; ++kb) {
        bf16x8 vf = ldb8(&Vl[(db * 16 + id15) * KSTR + kb * 32 + quad * 8]);
        oacc[0][db] = mfma16(pf[0][kb], vf, oacc[0][db]);
        oacc[1][db] = mfma16(pf[1][kb], vf, oacc[1][db]);
      }
    }
  }

  // Epilogue: lacc reg r holds l(row=quad*4+r) — same rows as oacc regs. No shuffles.
#pragma unroll
  for (int rg = 0; rg < 2; ++rg) {
#pragma unroll
    for (int r = 0; r < 4; ++r) {
      float linv = 1.0f / lacc[rg][r];
      int n = q0 + rg * 16 + quad * 4 + r;
#pragma unroll
      for (int db = 0; db < 4; ++db)
        O[(size_t)(b * N_ + n) * C_ + h * 64 + db * 16 + id15] = (unsigned short)f2bs(oacc[rg][db][r] * linv);
    }
  }
}

extern "C" void kernel_launch(void* const* d_in, const int* in_sizes, int n_in,
                              void* d_out, int out_size, void* d_ws, size_t ws_size,
                              hipStream_t stream) {
  const float* x_q = (const float*)d_in[0];
  const float* x_k = (const float*)d_in[1];
  const float* x_v = (const float*)d_in[2];
  const float* x_u = (const float*)d_in[3];
  const float* Wq  = (const float*)d_in[4];
  const float* Wk  = (const float*)d_in[5];
  const float* Wv  = (const float*)d_in[6];
  const float* Wp  = (const float*)d_in[7];
  const float* bp  = (const float*)d_in[8];

  char* ws = (char*)d_ws;
  size_t off = 0;
  auto alloc = [&](size_t bytes) {
    char* p = ws + off;
    off += (bytes + 255) & ~(size_t)255;
    return p;
  };
  unsigned short* wq16 = (unsigned short*)alloc((size_t)C_ * C_ * 2);
  unsigned short* wk16 = (unsigned short*)alloc((size_t)C_ * C_ * 2);
  unsigned short* wv16 = (unsigned short*)alloc((size_t)C_ * C_ * 2);
  unsigned short* wp16 = (unsigned short*)alloc((size_t)C_ * C_ * 2);
  float*          ucp  = (float*)alloc((size_t)B_ * N_ * 4);
  unsigned short* xq16 = (unsigned short*)alloc((size_t)B_ * N_ * C_ * 2);
  unsigned short* xk16 = (unsigned short*)alloc((size_t)B_ * N_ * C_ * 2);
  unsigned short* xv16 = (unsigned short*)alloc((size_t)B_ * N_ * C_ * 2);
  unsigned short* q_s  = (unsigned short*)alloc((size_t)B_ * N_ * C_ * 2);
  unsigned short* k_s  = (unsigned short*)alloc((size_t)B_ * N_ * C_ * 2);
  unsigned short* vT   = (unsigned short*)alloc((size_t)B_ * N_ * C_ * 2);
  unsigned short* ao   = (unsigned short*)alloc((size_t)B_ * N_ * C_ * 2);

  convx_kernel<<<dim3(6144, 3), 256, 0, stream>>>(x_q, x_k, x_v, xq16, xk16, xv16);
  convw_kernel<<<dim3(576, 4), 256, 0, stream>>>(Wq, Wk, Wv, Wp, wq16, wk16, wv16, wp16);
  uc_kernel<<<dim3(2048), 256, 0, stream>>>(x_u, ucp);
  gemm_qkv<<<dim3(6, 64, 3), 256, 0, stream>>>(xq16, xk16, xv16, wq16, wk16, wv16,
                                               q_s, k_s, vT, ucp);
  attn_kernel<<<dim3(16, 48), 256, 0, stream>>>(q_s, k_s, vT, ao);
  gemm_out<<<dim3(6, 64), 256, 0, stream>>>(ao, wp16, (float*)d_out, bp);
}

// Round 7
// 313.497 us; speedup vs baseline: 1.5921x; 1.5921x over previous
//
#include <hip/hip_runtime.h>
#include <hip/hip_bf16.h>
#include <cstdint>

// Problem constants
#define B_ 4
#define N_ 2048
#define C_ 768
#define H_ 12
#define D_ 64
// SCALE = D^-0.5 = 0.125; folded exp2 scale = 0.125 * log2(e)
#define QSCALE 0.18033688011112042f

typedef __bf16 bf16x8 __attribute__((ext_vector_type(8)));
typedef float f32x4 __attribute__((ext_vector_type(4)));

// RNE float -> bf16 bits (branchless; inputs are finite)
__device__ __forceinline__ unsigned f2bs(float x) {
  unsigned u = __builtin_bit_cast(unsigned, x);
  unsigned r = (u + 0x7fffu + ((u >> 16) & 1u)) >> 16;
  return r;
}

__device__ __forceinline__ bf16x8 ldb8(const unsigned short* p) {
  return __builtin_bit_cast(bf16x8, *(const uint4*)p);
}

__device__ __forceinline__ f32x4 mfma16(bf16x8 a, bf16x8 b, f32x4 c) {
  return __builtin_amdgcn_mfma_f32_16x16x32_bf16(a, b, c, 0, 0, 0);
}

// async global->LDS, 16B per lane. lds base must be wave-uniform; HW deposits
// lane i at lds + i*16 (m97/m104 semantics).
__device__ __forceinline__ void async16(const unsigned short* g, unsigned short* l) {
  __builtin_amdgcn_global_load_lds(
      (const __attribute__((address_space(1))) unsigned int*)g,
      (__attribute__((address_space(3))) unsigned int*)l, 16, 0, 0);
}

// ---------------- x conversion: 3 x (B*N*C) f32 -> bf16 ----------------
__global__ void convx_kernel(const float* __restrict__ s0, const float* __restrict__ s1,
                             const float* __restrict__ s2,
                             unsigned short* __restrict__ d0, unsigned short* __restrict__ d1,
                             unsigned short* __restrict__ d2) {
  const float* s; unsigned short* d;
  switch (blockIdx.y) {
    case 0: s = s0; d = d0; break;
    case 1: s = s1; d = d1; break;
    default: s = s2; d = d2; break;
  }
  int i = (blockIdx.x * 256 + threadIdx.x) * 4;   // grid.x=6144 covers 6291456 exactly
  float4 v = *(const float4*)(s + i);
  ushort4 h;
  h.x = (unsigned short)f2bs(v.x); h.y = (unsigned short)f2bs(v.y);
  h.z = (unsigned short)f2bs(v.z); h.w = (unsigned short)f2bs(v.w);
  *(ushort4*)(d + i) = h;
}

// ---------------- weight conversion: 4 x (768x768) f32 -> bf16 ----------------
__global__ void convw_kernel(const float* __restrict__ s0, const float* __restrict__ s1,
                             const float* __restrict__ s2, const float* __restrict__ s3,
                             unsigned short* __restrict__ d0, unsigned short* __restrict__ d1,
                             unsigned short* __restrict__ d2, unsigned short* __restrict__ d3) {
  const float* s; unsigned short* d;
  switch (blockIdx.y) {
    case 0: s = s0; d = d0; break;
    case 1: s = s1; d = d1; break;
    case 2: s = s2; d = d2; break;
    default: s = s3; d = d3; break;
  }
  int i = (blockIdx.x * 256 + threadIdx.x) * 4;   // grid.x=576 -> 589824 exactly
  float4 v = *(const float4*)(s + i);
  ushort4 h;
  h.x = (unsigned short)f2bs(v.x); h.y = (unsigned short)f2bs(v.y);
  h.z = (unsigned short)f2bs(v.z); h.w = (unsigned short)f2bs(v.w);
  *(ushort4*)(d + i) = h;
}

// ---------------- uc[b,n] = mean over C of x_u ----------------
__global__ void uc_kernel(const float* __restrict__ xu, float* __restrict__ uc) {
  int w = threadIdx.x >> 6, lane = threadIdx.x & 63;
  int row = blockIdx.x * 4 + w;                   // grid 2048 -> 8192 rows
  const float* p = xu + (size_t)row * C_;
  float s = 0.f;
#pragma unroll
  for (int i = 0; i < 3; ++i) {
    float4 v = *(const float4*)(p + (i * 64 + lane) * 4);
    s += v.x + v.y + v.z + v.w;
  }
#pragma unroll
  for (int off = 1; off < 64; off <<= 1) s += __shfl_xor(s, off);
  if (lane == 0) uc[row] = s * (1.f / 768.f);
}

// ---------------- GEMM mainloop (128x128 tile, BK=64, async16 staging) -------------
// A [8192 x 768] bf16 row-major, W [768 x 768] bf16 row-major (NT gemm).
// LDS layout: two 32-col panels per BK=64 tile: panel kk at offset kk*4096 shorts,
// [row][32] row-major. Granule g = s*256+tid: dest shorts [g*8..g*8+8),
// src row=(g>>2)&127, col=((g>>9)<<5)|((g&3)<<3).  (R5-measured structure.)
__device__ __forceinline__ void gemm_mainloop(
    const unsigned short* __restrict__ A, const unsigned short* __restrict__ W,
    int m0, int n0, unsigned short* Al, unsigned short* Bl,
    int tid, int wm, int wn, int quad, int id15, f32x4 (*acc)[4]) {
  const int wb = tid & 192;                        // wave-uniform granule base (within 256)
  const unsigned short* ap[4];
  const unsigned short* bp[4];
#pragma unroll
  for (int s = 0; s < 4; ++s) {
    int g = s * 256 + tid;
    int row = (g >> 2) & 127;
    int col = ((g >> 9) << 5) | ((g & 3) << 3);
    ap[s] = A + (size_t)(m0 + row) * C_ + col;
    bp[s] = W + (size_t)(n0 + row) * C_ + col;
  }

  for (int kt = 0; kt < C_; kt += 64) {
    __syncthreads();
#pragma unroll
    for (int s = 0; s < 4; ++s) {
      async16(ap[s] + kt, Al + (s * 256 + wb) * 8);
      async16(bp[s] + kt, Bl + (s * 256 + wb) * 8);
    }
    __syncthreads();

#pragma unroll
    for (int kk = 0; kk < 2; ++kk) {
      bf16x8 af[4], bfr[4];
#pragma unroll
      for (int i = 0; i < 4; ++i)
        af[i]  = ldb8(&Al[kk * 4096 + (wm + i * 16 + id15) * 32 + quad * 8]);
#pragma unroll
      for (int j = 0; j < 4; ++j)
        bfr[j] = ldb8(&Bl[kk * 4096 + (wn + j * 16 + id15) * 32 + quad * 8]);
#pragma unroll
      for (int i = 0; i < 4; ++i)
#pragma unroll
        for (int j = 0; j < 4; ++j)
          acc[i][j] = mfma16(af[i], bfr[j], acc[i][j]);
    }
  }
}

// ---------------- fused QKV projection ----------------
// z=0: Q = x_q@Wq^T * QSCALE*uc (log2e folded), bf16 [B*N, C]
// z=1: K = x_k@Wk^T,            bf16 [B*N, C]
// z=2: V^T[b*C+o][n] = x_v@Wv^T bf16, written COALESCED via LDS transpose
//      (scattered 2B stores caused ~30x write amplification: 370 MB WRITE_SIZE, R6 profile)
#define TSTR 136   // transpose LDS row stride (shorts): 272 B, 16B-aligned rows
__global__ __launch_bounds__(256, 3) void gemm_qkv(
    const unsigned short* __restrict__ xq, const unsigned short* __restrict__ xk,
    const unsigned short* __restrict__ xv,
    const unsigned short* __restrict__ wq, const unsigned short* __restrict__ wk,
    const unsigned short* __restrict__ wv,
    unsigned short* __restrict__ oq, unsigned short* __restrict__ ok,
    unsigned short* __restrict__ ov, const float* __restrict__ uc) {
  __shared__ __align__(16) unsigned short S[128 * TSTR];   // 34816 B; aliases Al/Bl
  unsigned short* Al = S;
  unsigned short* Bl = S + 8192;
  const int tid = threadIdx.x;
  const int w = tid >> 6, lane = tid & 63, quad = lane >> 4, id15 = lane & 15;
  const int wm = (w >> 1) << 6, wn = (w & 1) << 6;
  const int m0 = blockIdx.y << 7, n0 = blockIdx.x << 7;
  const int z = blockIdx.z;

  const unsigned short* A = (z == 0) ? xq : (z == 1) ? xk : xv;
  const unsigned short* W = (z == 0) ? wq : (z == 1) ? wk : wv;

  f32x4 acc[4][4] = {};
  gemm_mainloop(A, W, m0, n0, Al, Bl, tid, wm, wn, quad, id15, acc);

  if (z == 2) {
    // transpose through LDS: S[gn_local][n_local], then coalesced row writes
    __syncthreads();
#pragma unroll
    for (int i = 0; i < 4; ++i)
#pragma unroll
      for (int j = 0; j < 4; ++j) {
        uint2 u;
        u.x = f2bs(acc[i][j][0]) | (f2bs(acc[i][j][1]) << 16);
        u.y = f2bs(acc[i][j][2]) | (f2bs(acc[i][j][3]) << 16);
        *(uint2*)&S[(wn + j * 16 + id15) * TSTR + wm + i * 16 + quad * 4] = u;
      }
    __syncthreads();
    const int b = m0 >> 11, nb = m0 & (N_ - 1);
#pragma unroll
    for (int s = 0; s < 8; ++s) {
      int c = s * 256 + tid;               // 2048 chunks of 8 shorts
      int row = c >> 4, o = (c & 15) << 3;
      *(uint4*)(ov + (size_t)(b * C_ + n0 + row) * N_ + nb + o) = *(const uint4*)&S[row * TSTR + o];
    }
    return;
  }

#pragma unroll
  for (int i = 0; i < 4; ++i) {
#pragma unroll
    for (int j = 0; j < 4; ++j) {
#pragma unroll
      for (int r = 0; r < 4; ++r) {
        int gm = m0 + wm + i * 16 + quad * 4 + r;   // global row (b*N + n)
        int gn = n0 + wn + j * 16 + id15;           // global out channel
        float v = acc[i][j][r];
        if (z == 0) {
          v *= QSCALE * uc[gm];
          oq[(size_t)gm * C_ + gn] = (unsigned short)f2bs(v);
        } else {
          ok[(size_t)gm * C_ + gn] = (unsigned short)f2bs(v);
        }
      }
    }
  }
}

// ---------------- output projection: out = ao@Wp^T + bp, f32 ----------------
__global__ __launch_bounds__(256, 3) void gemm_out(
    const unsigned short* __restrict__ ao, const unsigned short* __restrict__ wp,
    float* __restrict__ out, const float* __restrict__ bias) {
  __shared__ __align__(16) unsigned short Al[128 * 64];
  __shared__ __align__(16) unsigned short Bl[128 * 64];
  const int tid = threadIdx.x;
  const int w = tid >> 6, lane = tid & 63, quad = lane >> 4, id15 = lane & 15;
  const int wm = (w >> 1) << 6, wn = (w & 1) << 6;
  const int m0 = blockIdx.y << 7, n0 = blockIdx.x << 7;

  f32x4 acc[4][4] = {};
  gemm_mainloop(ao, wp, m0, n0, Al, Bl, tid, wm, wn, quad, id15, acc);

#pragma unroll
  for (int i = 0; i < 4; ++i) {
#pragma unroll
    for (int j = 0; j < 4; ++j) {
#pragma unroll
      for (int r = 0; r < 4; ++r) {
        int gm = m0 + wm + i * 16 + quad * 4 + r;
        int gn = n0 + wn + j * 16 + id15;
        out[(size_t)gm * C_ + gn] = acc[i][j][r] + bias[gn];
      }
    }
  }
}

// ---------------- Flash attention (S^T, exp2, MFMA-lsum) — R5-measured structure ----
// Q: [B,N,C] bf16 (pre-scaled by QSCALE*uc, log2e folded); K: [B,N,C] bf16;
// Vt: [B*C, N] bf16. O: [B,N,C] bf16.
// Grid: (N/128, B*H), block 256 (4 waves x 32 q-rows). K-chunks of 64.
#define KSTR 72   // K/V LDS row stride (shorts): 144 B, 16B-aligned rows
#define PSTR 72
__global__ __launch_bounds__(256, 3) void attn_kernel(
    const unsigned short* __restrict__ Q, const unsigned short* __restrict__ Kk,
    const unsigned short* __restrict__ Vt, unsigned short* __restrict__ O) {
  __shared__ __align__(16) unsigned short Kl[64 * KSTR];
  __shared__ __align__(16) unsigned short Vl[64 * KSTR];
  __shared__ __align__(16) unsigned short Pl[8][16 * PSTR];   // per (wave, rg)

  const int tid = threadIdx.x;
  const int w = tid >> 6, lane = tid & 63, quad = lane >> 4, id15 = lane & 15;
  const int bh = blockIdx.y;
  const int b = bh / H_, h = bh % H_;
  const int q0 = blockIdx.x * 128 + w * 32;

  bf16x8 qf[2][2];
#pragma unroll
  for (int rg = 0; rg < 2; ++rg)
#pragma unroll
    for (int kb = 0; kb < 2; ++kb)
      qf[rg][kb] = ldb8(Q + (size_t)(b * N_ + q0 + rg * 16 + id15) * C_ + h * 64 + kb * 32 + quad * 8);

  const uint4 onesu = {0x3F803F80u, 0x3F803F80u, 0x3F803F80u, 0x3F803F80u};
  const bf16x8 onesf = __builtin_bit_cast(bf16x8, onesu);

  f32x4 oacc[2][4] = {};
  f32x4 lacc[2] = {};

  const size_t kbase = (size_t)(b * N_) * C_ + h * 64;
  const size_t vbase = (size_t)(b * C_ + h * 64) * N_;
  const int srow0 = tid >> 3, srow1 = (256 + tid) >> 3;
  const int sseg0 = (tid & 7) << 3;

  unsigned short* Plw0 = &Pl[w * 2 + 0][0];
  unsigned short* Plw1 = &Pl[w * 2 + 1][0];

  for (int kc = 0; kc < N_; kc += 64) {
    __syncthreads();
    *(uint4*)&Kl[srow0 * KSTR + sseg0] = *(const uint4*)(Kk + kbase + (size_t)(kc + srow0) * C_ + sseg0);
    *(uint4*)&Kl[srow1 * KSTR + sseg0] = *(const uint4*)(Kk + kbase + (size_t)(kc + srow1) * C_ + sseg0);
    *(uint4*)&Vl[srow0 * KSTR + sseg0] = *(const uint4*)(Vt + vbase + (size_t)srow0 * N_ + kc + sseg0);
    *(uint4*)&Vl[srow1 * KSTR + sseg0] = *(const uint4*)(Vt + vbase + (size_t)srow1 * N_ + kc + sseg0);
    __syncthreads();

    // Phase 1: S^T for both row-groups, K-frags shared
    f32x4 sA[4], sB[4];
#pragma unroll
    for (int cb = 0; cb < 4; ++cb) {
      f32x4 a = {}, c = {};
#pragma unroll
      for (int kb = 0; kb < 2; ++kb) {
        bf16x8 kf = ldb8(&Kl[(cb * 16 + id15) * KSTR + kb * 32 + quad * 8]);
        a = mfma16(kf, qf[0][kb], a);
        c = mfma16(kf, qf[1][kb], c);
      }
      sA[cb] = a; sB[cb] = c;
    }

    // Phase 2: exp2 + truncate-pack (1 v_perm per pair) + vectorized P write
#pragma unroll
    for (int rg = 0; rg < 2; ++rg) {
      f32x4* s4 = (rg == 0) ? sA : sB;
      unsigned short* Plw = (rg == 0) ? Plw0 : Plw1;
#pragma unroll
      for (int cb = 0; cb < 4; ++cb) {
        unsigned p0 = __builtin_bit_cast(unsigned, exp2f(s4[cb][0]));
        unsigned p1 = __builtin_bit_cast(unsigned, exp2f(s4[cb][1]));
        unsigned p2 = __builtin_bit_cast(unsigned, exp2f(s4[cb][2]));
        unsigned p3 = __builtin_bit_cast(unsigned, exp2f(s4[cb][3]));
        uint2 u;
        u.x = __builtin_amdgcn_perm(p1, p0, 0x07060302u);
        u.y = __builtin_amdgcn_perm(p3, p2, 0x07060302u);
        *(uint2*)&Plw[id15 * PSTR + cb * 16 + quad * 4] = u;
      }
    }

    // Phase 3: P fragments (A-operand)
    bf16x8 pf[2][2];
#pragma unroll
    for (int kb = 0; kb < 2; ++kb) {
      pf[0][kb] = ldb8(&Plw0[id15 * PSTR + kb * 32 + quad * 8]);
      pf[1][kb] = ldb8(&Plw1[id15 * PSTR + kb * 32 + quad * 8]);
    }

    // Phase 4: PV + ones-MFMA row-sum (matrix pipe), V-frags shared
#pragma unroll
    for (int kb = 0; kb < 2; ++kb) {
      lacc[0] = mfma16(pf[0][kb], onesf, lacc[0]);
      lacc[1] = mfma16(pf[1][kb], onesf, lacc[1]);
    }
#pragma unroll
    for (int db = 0; db < 4; ++db) {
#pragma unroll
      for (int kb = 0; kb < 2; ++kb) {
        bf16x8 vf = ldb8(&Vl[(db * 16 + id15) * KSTR + kb * 32 + quad * 8]);
        oacc[0][db] = mfma16(pf[0][kb], vf, oacc[0][db]);
        oacc[1][db] = mfma16(pf[1][kb], vf, oacc[1][db]);
      }
    }
  }

  // Epilogue: lacc reg r holds l(row=quad*4+r) — same rows as oacc regs. No shuffles.
#pragma unroll
  for (int rg = 0; rg < 2; ++rg) {
#pragma unroll
    for (int r = 0; r < 4; ++r) {
      float linv = 1.0f / lacc[rg][r];
      int n = q0 + rg * 16 + quad * 4 + r;
#pragma unroll
      for (int db = 0; db < 4; ++db)
        O[(size_t)(b * N_ + n) * C_ + h * 64 + db * 16 + id15] = (unsigned short)f2bs(oacc[rg][db][r] * linv);
    }
  }
}

extern "C" void kernel_launch(void* const* d_in, const int* in_sizes, int n_in,
                              void* d_out, int out_size, void* d_ws, size_t ws_size,
                              hipStream_t stream) {
  const float* x_q = (const float*)d_in[0];
  const float* x_k = (const float*)d_in[1];
  const float* x_v = (const float*)d_in[2];
  const float* x_u = (const float*)d_in[3];
  const float* Wq  = (const float*)d_in[4];
  const float* Wk  = (const float*)d_in[5];
  const float* Wv  = (const float*)d_in[6];
  const float* Wp  = (const float*)d_in[7];
  const float* bp  = (const float*)d_in[8];

  char* ws = (char*)d_ws;
  size_t off = 0;
  auto alloc = [&](size_t bytes) {
    char* p = ws + off;
    off += (bytes + 255) & ~(size_t)255;
    return p;
  };
  unsigned short* wq16 = (unsigned short*)alloc((size_t)C_ * C_ * 2);
  unsigned short* wk16 = (unsigned short*)alloc((size_t)C_ * C_ * 2);
  unsigned short* wv16 = (unsigned short*)alloc((size_t)C_ * C_ * 2);
  unsigned short* wp16 = (unsigned short*)alloc((size_t)C_ * C_ * 2);
  float*          ucp  = (float*)alloc((size_t)B_ * N_ * 4);
  unsigned short* xq16 = (unsigned short*)alloc((size_t)B_ * N_ * C_ * 2);
  unsigned short* xk16 = (unsigned short*)alloc((size_t)B_ * N_ * C_ * 2);
  unsigned short* xv16 = (unsigned short*)alloc((size_t)B_ * N_ * C_ * 2);
  unsigned short* q_s  = (unsigned short*)alloc((size_t)B_ * N_ * C_ * 2);
  unsigned short* k_s  = (unsigned short*)alloc((size_t)B_ * N_ * C_ * 2);
  unsigned short* vT   = (unsigned short*)alloc((size_t)B_ * N_ * C_ * 2);
  unsigned short* ao   = (unsigned short*)alloc((size_t)B_ * N_ * C_ * 2);

  convx_kernel<<<dim3(6144, 3), 256, 0, stream>>>(x_q, x_k, x_v, xq16, xk16, xv16);
  convw_kernel<<<dim3(576, 4), 256, 0, stream>>>(Wq, Wk, Wv, Wp, wq16, wk16, wv16, wp16);
  uc_kernel<<<dim3(2048), 256, 0, stream>>>(x_u, ucp);
  gemm_qkv<<<dim3(6, 64, 3), 256, 0, stream>>>(xq16, xk16, xv16, wq16, wk16, wv16,
                                               q_s, k_s, vT, ucp);
  attn_kernel<<<dim3(16, 48), 256, 0, stream>>>(q_s, k_s, vT, ao);
  gemm_out<<<dim3(6, 64), 256, 0, stream>>>(ao, wp16, (float*)d_out, bp);
}

// Round 8
// 296.435 us; speedup vs baseline: 1.6838x; 1.0576x over previous
//
#include <hip/hip_runtime.h>
#include <hip/hip_bf16.h>
#include <cstdint>

// Problem constants
#define B_ 4
#define N_ 2048
#define C_ 768
#define H_ 12
#define D_ 64
// SCALE = D^-0.5 = 0.125; folded exp2 scale = 0.125 * log2(e)
#define QSCALE 0.18033688011112042f

typedef __bf16 bf16x8 __attribute__((ext_vector_type(8)));
typedef float f32x4 __attribute__((ext_vector_type(4)));

// RNE float -> bf16 bits (branchless; inputs are finite)
__device__ __forceinline__ unsigned f2bs(float x) {
  unsigned u = __builtin_bit_cast(unsigned, x);
  unsigned r = (u + 0x7fffu + ((u >> 16) & 1u)) >> 16;
  return r;
}

__device__ __forceinline__ bf16x8 ldb8(const unsigned short* p) {
  return __builtin_bit_cast(bf16x8, *(const uint4*)p);
}

__device__ __forceinline__ f32x4 mfma16(bf16x8 a, bf16x8 b, f32x4 c) {
  return __builtin_amdgcn_mfma_f32_16x16x32_bf16(a, b, c, 0, 0, 0);
}

// async global->LDS, 16B per lane. lds base must be wave-uniform; HW deposits
// lane i at lds + i*16 (m97/m104 semantics).
__device__ __forceinline__ void async16(const unsigned short* g, unsigned short* l) {
  __builtin_amdgcn_global_load_lds(
      (const __attribute__((address_space(1))) unsigned int*)g,
      (__attribute__((address_space(3))) unsigned int*)l, 16, 0, 0);
}

// ---------------- fused prep: x/W f32->bf16 casts + uc row means ----------------
// blocks [0,18432): convert x_q/x_k/x_v (6144 blocks each)
// blocks [18432,20736): convert Wq/Wk/Wv/Wp (576 blocks each)
// blocks [20736,22784): uc[row] = mean(x_u row) (2048 blocks, 4 rows each)
__global__ void prep_kernel(
    const float* __restrict__ xq, const float* __restrict__ xk,
    const float* __restrict__ xv, const float* __restrict__ xu,
    const float* __restrict__ Wq, const float* __restrict__ Wk,
    const float* __restrict__ Wv, const float* __restrict__ Wp,
    unsigned short* __restrict__ dxq, unsigned short* __restrict__ dxk,
    unsigned short* __restrict__ dxv,
    unsigned short* __restrict__ dwq, unsigned short* __restrict__ dwk,
    unsigned short* __restrict__ dwv, unsigned short* __restrict__ dwp,
    float* __restrict__ uc) {
  const int id = blockIdx.x;
  if (id < 18432) {
    const float* s = (id < 6144) ? xq : (id < 12288) ? xk : xv;
    unsigned short* d = (id < 6144) ? dxq : (id < 12288) ? dxk : dxv;
    int i = ((id % 6144) * 256 + threadIdx.x) * 4;
    float4 v = *(const float4*)(s + i);
    ushort4 h;
    h.x = (unsigned short)f2bs(v.x); h.y = (unsigned short)f2bs(v.y);
    h.z = (unsigned short)f2bs(v.z); h.w = (unsigned short)f2bs(v.w);
    *(ushort4*)(d + i) = h;
  } else if (id < 20736) {
    int sub = id - 18432;
    int which = sub / 576;
    const float* s = (which == 0) ? Wq : (which == 1) ? Wk : (which == 2) ? Wv : Wp;
    unsigned short* d = (which == 0) ? dwq : (which == 1) ? dwk : (which == 2) ? dwv : dwp;
    int i = ((sub % 576) * 256 + threadIdx.x) * 4;
    float4 v = *(const float4*)(s + i);
    ushort4 h;
    h.x = (unsigned short)f2bs(v.x); h.y = (unsigned short)f2bs(v.y);
    h.z = (unsigned short)f2bs(v.z); h.w = (unsigned short)f2bs(v.w);
    *(ushort4*)(d + i) = h;
  } else {
    int sub = id - 20736;
    int w = threadIdx.x >> 6, lane = threadIdx.x & 63;
    int row = sub * 4 + w;
    const float* p = xu + (size_t)row * C_;
    float s = 0.f;
#pragma unroll
    for (int i = 0; i < 3; ++i) {
      float4 v = *(const float4*)(p + (i * 64 + lane) * 4);
      s += v.x + v.y + v.z + v.w;
    }
#pragma unroll
    for (int off = 1; off < 64; off <<= 1) s += __shfl_xor(s, off);
    if (lane == 0) uc[row] = s * (1.f / 768.f);
  }
}

// ---------------- GEMM mainloop (128x128 tile, BK=64, async16 staging) -------------
// A [8192 x 768] bf16 row-major, W [768 x 768] bf16 row-major (NT gemm).
// LDS: two 32-col panels per BK=64 tile (panel kk at kk*4096 shorts, [row][32]).
// Granule g = s*256+tid: dest shorts [g*8..g*8+8), src row=(g>>2)&127,
// col=((g>>9)<<5)|((g&3)<<3).  (R5/R7-measured structure.)
__device__ __forceinline__ void gemm_mainloop(
    const unsigned short* __restrict__ A, const unsigned short* __restrict__ W,
    int m0, int n0, unsigned short* Al, unsigned short* Bl,
    int tid, int wm, int wn, int quad, int id15, f32x4 (*acc)[4]) {
  const int wb = tid & 192;                        // wave-uniform granule base
  const unsigned short* ap[4];
  const unsigned short* bp[4];
#pragma unroll
  for (int s = 0; s < 4; ++s) {
    int g = s * 256 + tid;
    int row = (g >> 2) & 127;
    int col = ((g >> 9) << 5) | ((g & 3) << 3);
    ap[s] = A + (size_t)(m0 + row) * C_ + col;
    bp[s] = W + (size_t)(n0 + row) * C_ + col;
  }

  for (int kt = 0; kt < C_; kt += 64) {
    __syncthreads();
#pragma unroll
    for (int s = 0; s < 4; ++s) {
      async16(ap[s] + kt, Al + (s * 256 + wb) * 8);
      async16(bp[s] + kt, Bl + (s * 256 + wb) * 8);
    }
    __syncthreads();

#pragma unroll
    for (int kk = 0; kk < 2; ++kk) {
      bf16x8 af[4], bfr[4];
#pragma unroll
      for (int i = 0; i < 4; ++i)
        af[i]  = ldb8(&Al[kk * 4096 + (wm + i * 16 + id15) * 32 + quad * 8]);
#pragma unroll
      for (int j = 0; j < 4; ++j)
        bfr[j] = ldb8(&Bl[kk * 4096 + (wn + j * 16 + id15) * 32 + quad * 8]);
#pragma unroll
      for (int i = 0; i < 4; ++i)
#pragma unroll
        for (int j = 0; j < 4; ++j)
          acc[i][j] = mfma16(af[i], bfr[j], acc[i][j]);
    }
  }
}

// ---------------- fused QKV projection (XCD-swizzled 1D grid, 1152 blocks) ---------
// Blocks sharing an A-tile (all 6 n) are placed on the SAME XCD so its L2 serves
// the A re-reads (R6 profile: FETCH 169 MB vs ~41 MB ideal = cross-XCD duplication).
// z=0: Q = x_q@Wq^T * QSCALE*uc; z=1: K; z=2: V^T via LDS transpose, coalesced.
#define TSTR 136   // transpose LDS row stride (shorts): 272 B, 16B-aligned rows
__global__ __launch_bounds__(256, 3) void gemm_qkv(
    const unsigned short* __restrict__ xq, const unsigned short* __restrict__ xk,
    const unsigned short* __restrict__ xv,
    const unsigned short* __restrict__ wq, const unsigned short* __restrict__ wk,
    const unsigned short* __restrict__ wv,
    unsigned short* __restrict__ oq, unsigned short* __restrict__ ok,
    unsigned short* __restrict__ ov, const float* __restrict__ uc) {
  __shared__ __align__(16) unsigned short S[128 * TSTR];   // 34816 B; aliases Al/Bl
  unsigned short* Al = S;
  unsigned short* Bl = S + 8192;
  const int tid = threadIdx.x;
  const int w = tid >> 6, lane = tid & 63, quad = lane >> 4, id15 = lane & 15;
  const int wm = (w >> 1) << 6, wn = (w & 1) << 6;
  // XCD swizzle: xcd = id&7; within an XCD, n varies fastest for fixed (z,m)
  const int id = blockIdx.x;
  const int xcd = id & 7, slot = id >> 3;          // slot 0..143
  const int n0 = (slot % 6) << 7;
  const int gz = xcd * 24 + slot / 6;              // 0..191 = (z,m) pairs
  const int z = gz >> 6, m0 = (gz & 63) << 7;

  const unsigned short* A = (z == 0) ? xq : (z == 1) ? xk : xv;
  const unsigned short* W = (z == 0) ? wq : (z == 1) ? wk : wv;

  f32x4 acc[4][4] = {};
  gemm_mainloop(A, W, m0, n0, Al, Bl, tid, wm, wn, quad, id15, acc);

  if (z == 2) {
    // transpose through LDS: S[gn_local][n_local], then coalesced row writes
    __syncthreads();
#pragma unroll
    for (int i = 0; i < 4; ++i)
#pragma unroll
      for (int j = 0; j < 4; ++j) {
        uint2 u;
        u.x = f2bs(acc[i][j][0]) | (f2bs(acc[i][j][1]) << 16);
        u.y = f2bs(acc[i][j][2]) | (f2bs(acc[i][j][3]) << 16);
        *(uint2*)&S[(wn + j * 16 + id15) * TSTR + wm + i * 16 + quad * 4] = u;
      }
    __syncthreads();
    const int b = m0 >> 11, nb = m0 & (N_ - 1);
#pragma unroll
    for (int s = 0; s < 8; ++s) {
      int c = s * 256 + tid;               // 2048 chunks of 8 shorts
      int row = c >> 4, o = (c & 15) << 3;
      *(uint4*)(ov + (size_t)(b * C_ + n0 + row) * N_ + nb + o) = *(const uint4*)&S[row * TSTR + o];
    }
    return;
  }

#pragma unroll
  for (int i = 0; i < 4; ++i) {
#pragma unroll
    for (int j = 0; j < 4; ++j) {
#pragma unroll
      for (int r = 0; r < 4; ++r) {
        int gm = m0 + wm + i * 16 + quad * 4 + r;   // global row (b*N + n)
        int gn = n0 + wn + j * 16 + id15;           // global out channel
        float v = acc[i][j][r];
        if (z == 0) {
          v *= QSCALE * uc[gm];
          oq[(size_t)gm * C_ + gn] = (unsigned short)f2bs(v);
        } else {
          ok[(size_t)gm * C_ + gn] = (unsigned short)f2bs(v);
        }
      }
    }
  }
}

// ---------------- output projection: out = ao@Wp^T + bp, f32 ----------------
// Tile 64(M) x 128(N), BK=64 -> 768 blocks = 3/CU (was 384 = 1.5/CU tail).
// XCD swizzle: same-A-tile blocks (6 n) on one XCD.
__global__ __launch_bounds__(256, 4) void gemm_out(
    const unsigned short* __restrict__ ao, const unsigned short* __restrict__ wp,
    float* __restrict__ out, const float* __restrict__ bias) {
  __shared__ __align__(16) unsigned short Al[64 * 64];
  __shared__ __align__(16) unsigned short Bl[128 * 64];
  const int tid = threadIdx.x;
  const int w = tid >> 6, lane = tid & 63, quad = lane >> 4, id15 = lane & 15;
  const int wm = (w >> 1) << 5, wn = (w & 1) << 6;
  const int id = blockIdx.x;
  const int xcd = id & 7, slot = id >> 3;          // slot 0..95
  const int n0 = (slot % 6) << 7;
  const int m0 = (xcd * 16 + slot / 6) << 6;       // m-tile 0..127

  const int wb = tid & 192;
  const unsigned short* ap[2];
#pragma unroll
  for (int s = 0; s < 2; ++s) {                    // A: 64x64 tile, 512 granules
    int g = s * 256 + tid;
    int row = (g >> 2) & 63;
    int col = ((g >> 8) << 5) | ((g & 3) << 3);
    ap[s] = ao + (size_t)(m0 + row) * C_ + col;
  }
  const unsigned short* bp[4];
#pragma unroll
  for (int s = 0; s < 4; ++s) {                    // B: 128x64 tile, 1024 granules
    int g = s * 256 + tid;
    int row = (g >> 2) & 127;
    int col = ((g >> 9) << 5) | ((g & 3) << 3);
    bp[s] = wp + (size_t)(n0 + row) * C_ + col;
  }

  f32x4 acc[2][4] = {};
  for (int kt = 0; kt < C_; kt += 64) {
    __syncthreads();
#pragma unroll
    for (int s = 0; s < 2; ++s) async16(ap[s] + kt, Al + (s * 256 + wb) * 8);
#pragma unroll
    for (int s = 0; s < 4; ++s) async16(bp[s] + kt, Bl + (s * 256 + wb) * 8);
    __syncthreads();

#pragma unroll
    for (int kk = 0; kk < 2; ++kk) {
      bf16x8 af[2], bfr[4];
#pragma unroll
      for (int i = 0; i < 2; ++i)
        af[i]  = ldb8(&Al[kk * 2048 + (wm + i * 16 + id15) * 32 + quad * 8]);
#pragma unroll
      for (int j = 0; j < 4; ++j)
        bfr[j] = ldb8(&Bl[kk * 4096 + (wn + j * 16 + id15) * 32 + quad * 8]);
#pragma unroll
      for (int i = 0; i < 2; ++i)
#pragma unroll
        for (int j = 0; j < 4; ++j)
          acc[i][j] = mfma16(af[i], bfr[j], acc[i][j]);
    }
  }

#pragma unroll
  for (int i = 0; i < 2; ++i) {
#pragma unroll
    for (int j = 0; j < 4; ++j) {
#pragma unroll
      for (int r = 0; r < 4; ++r) {
        int gm = m0 + wm + i * 16 + quad * 4 + r;
        int gn = n0 + wn + j * 16 + id15;
        out[(size_t)gm * C_ + gn] = acc[i][j][r] + bias[gn];
      }
    }
  }
}

// ---------------- Flash attention (S^T, exp2, MFMA-lsum) — R5/R7 structure ---------
// XCD-swizzled 1D grid (768): all 16 q-tiles of a (b,h) on one XCD so its KV
// stays in that XCD's L2 (R7 FETCH 104 MB vs 37.5 ideal).
#define KSTR 72   // K/V LDS row stride (shorts): 144 B, 16B-aligned rows
#define PSTR 72
__global__ __launch_bounds__(256, 3) void attn_kernel(
    const unsigned short* __restrict__ Q, const unsigned short* __restrict__ Kk,
    const unsigned short* __restrict__ Vt, unsigned short* __restrict__ O) {
  __shared__ __align__(16) unsigned short Kl[64 * KSTR];
  __shared__ __align__(16) unsigned short Vl[64 * KSTR];
  __shared__ __align__(16) unsigned short Pl[8][16 * PSTR];   // per (wave, rg)

  const int tid = threadIdx.x;
  const int w = tid >> 6, lane = tid & 63, quad = lane >> 4, id15 = lane & 15;
  const int id = blockIdx.x;
  const int xcd = id & 7, slot = id >> 3;          // slot 0..95
  const int bh = xcd * 6 + (slot >> 4);            // 0..47
  const int qt = slot & 15;
  const int b = bh / H_, h = bh % H_;
  const int q0 = qt * 128 + w * 32;

  bf16x8 qf[2][2];
#pragma unroll
  for (int rg = 0; rg < 2; ++rg)
#pragma unroll
    for (int kb = 0; kb < 2; ++kb)
      qf[rg][kb] = ldb8(Q + (size_t)(b * N_ + q0 + rg * 16 + id15) * C_ + h * 64 + kb * 32 + quad * 8);

  const uint4 onesu = {0x3F803F80u, 0x3F803F80u, 0x3F803F80u, 0x3F803F80u};
  const bf16x8 onesf = __builtin_bit_cast(bf16x8, onesu);

  f32x4 oacc[2][4] = {};
  f32x4 lacc[2] = {};

  const size_t kbase = (size_t)(b * N_) * C_ + h * 64;
  const size_t vbase = (size_t)(b * C_ + h * 64) * N_;
  const int srow0 = tid >> 3, srow1 = (256 + tid) >> 3;
  const int sseg0 = (tid & 7) << 3;

  unsigned short* Plw0 = &Pl[w * 2 + 0][0];
  unsigned short* Plw1 = &Pl[w * 2 + 1][0];

  for (int kc = 0; kc < N_; kc += 64) {
    __syncthreads();
    *(uint4*)&Kl[srow0 * KSTR + sseg0] = *(const uint4*)(Kk + kbase + (size_t)(kc + srow0) * C_ + sseg0);
    *(uint4*)&Kl[srow1 * KSTR + sseg0] = *(const uint4*)(Kk + kbase + (size_t)(kc + srow1) * C_ + sseg0);
    *(uint4*)&Vl[srow0 * KSTR + sseg0] = *(const uint4*)(Vt + vbase + (size_t)srow0 * N_ + kc + sseg0);
    *(uint4*)&Vl[srow1 * KSTR + sseg0] = *(const uint4*)(Vt + vbase + (size_t)srow1 * N_ + kc + sseg0);
    __syncthreads();

    // Phase 1: S^T for both row-groups, K-frags shared
    f32x4 sA[4], sB[4];
#pragma unroll
    for (int cb = 0; cb < 4; ++cb) {
      f32x4 a = {}, c = {};
#pragma unroll
      for (int kb = 0; kb < 2; ++kb) {
        bf16x8 kf = ldb8(&Kl[(cb * 16 + id15) * KSTR + kb * 32 + quad * 8]);
        a = mfma16(kf, qf[0][kb], a);
        c = mfma16(kf, qf[1][kb], c);
      }
      sA[cb] = a; sB[cb] = c;
    }

    // Phase 2: exp2 + truncate-pack (1 v_perm per pair) + vectorized P write
#pragma unroll
    for (int rg = 0; rg < 2; ++rg) {
      f32x4* s4 = (rg == 0) ? sA : sB;
      unsigned short* Plw = (rg == 0) ? Plw0 : Plw1;
#pragma unroll
      for (int cb = 0; cb < 4; ++cb) {
        unsigned p0 = __builtin_bit_cast(unsigned, exp2f(s4[cb][0]));
        unsigned p1 = __builtin_bit_cast(unsigned, exp2f(s4[cb][1]));
        unsigned p2 = __builtin_bit_cast(unsigned, exp2f(s4[cb][2]));
        unsigned p3 = __builtin_bit_cast(unsigned, exp2f(s4[cb][3]));
        uint2 u;
        u.x = __builtin_amdgcn_perm(p1, p0, 0x07060302u);
        u.y = __builtin_amdgcn_perm(p3, p2, 0x07060302u);
        *(uint2*)&Plw[id15 * PSTR + cb * 16 + quad * 4] = u;
      }
    }

    // Phase 3: P fragments (A-operand)
    bf16x8 pf[2][2];
#pragma unroll
    for (int kb = 0; kb < 2; ++kb) {
      pf[0][kb] = ldb8(&Plw0[id15 * PSTR + kb * 32 + quad * 8]);
      pf[1][kb] = ldb8(&Plw1[id15 * PSTR + kb * 32 + quad * 8]);
    }

    // Phase 4: PV + ones-MFMA row-sum (matrix pipe), V-frags shared
#pragma unroll
    for (int kb = 0; kb < 2; ++kb) {
      lacc[0] = mfma16(pf[0][kb], onesf, lacc[0]);
      lacc[1] = mfma16(pf[1][kb], onesf, lacc[1]);
    }
#pragma unroll
    for (int db = 0; db < 4; ++db) {
#pragma unroll
      for (int kb = 0; kb < 2; ++kb) {
        bf16x8 vf = ldb8(&Vl[(db * 16 + id15) * KSTR + kb * 32 + quad * 8]);
        oacc[0][db] = mfma16(pf[0][kb], vf, oacc[0][db]);
        oacc[1][db] = mfma16(pf[1][kb], vf, oacc[1][db]);
      }
    }
  }

  // Epilogue: lacc reg r holds l(row=quad*4+r) — same rows as oacc regs. No shuffles.
#pragma unroll
  for (int rg = 0; rg < 2; ++rg) {
#pragma unroll
    for (int r = 0; r < 4; ++r) {
      float linv = 1.0f / lacc[rg][r];
      int n = q0 + rg * 16 + quad * 4 + r;
#pragma unroll
      for (int db = 0; db < 4; ++db)
        O[(size_t)(b * N_ + n) * C_ + h * 64 + db * 16 + id15] = (unsigned short)f2bs(oacc[rg][db][r] * linv);
    }
  }
}

extern "C" void kernel_launch(void* const* d_in, const int* in_sizes, int n_in,
                              void* d_out, int out_size, void* d_ws, size_t ws_size,
                              hipStream_t stream) {
  const float* x_q = (const float*)d_in[0];
  const float* x_k = (const float*)d_in[1];
  const float* x_v = (const float*)d_in[2];
  const float* x_u = (const float*)d_in[3];
  const float* Wq  = (const float*)d_in[4];
  const float* Wk  = (const float*)d_in[5];
  const float* Wv  = (const float*)d_in[6];
  const float* Wp  = (const float*)d_in[7];
  const float* bp  = (const float*)d_in[8];

  char* ws = (char*)d_ws;
  size_t off = 0;
  auto alloc = [&](size_t bytes) {
    char* p = ws + off;
    off += (bytes + 255) & ~(size_t)255;
    return p;
  };
  unsigned short* wq16 = (unsigned short*)alloc((size_t)C_ * C_ * 2);
  unsigned short* wk16 = (unsigned short*)alloc((size_t)C_ * C_ * 2);
  unsigned short* wv16 = (unsigned short*)alloc((size_t)C_ * C_ * 2);
  unsigned short* wp16 = (unsigned short*)alloc((size_t)C_ * C_ * 2);
  float*          ucp  = (float*)alloc((size_t)B_ * N_ * 4);
  unsigned short* xq16 = (unsigned short*)alloc((size_t)B_ * N_ * C_ * 2);
  unsigned short* xk16 = (unsigned short*)alloc((size_t)B_ * N_ * C_ * 2);
  unsigned short* xv16 = (unsigned short*)alloc((size_t)B_ * N_ * C_ * 2);
  unsigned short* q_s  = (unsigned short*)alloc((size_t)B_ * N_ * C_ * 2);
  unsigned short* k_s  = (unsigned short*)alloc((size_t)B_ * N_ * C_ * 2);
  unsigned short* vT   = (unsigned short*)alloc((size_t)B_ * N_ * C_ * 2);
  unsigned short* ao   = (unsigned short*)alloc((size_t)B_ * N_ * C_ * 2);

  prep_kernel<<<dim3(22784), 256, 0, stream>>>(x_q, x_k, x_v, x_u, Wq, Wk, Wv, Wp,
                                               xq16, xk16, xv16,
                                               wq16, wk16, wv16, wp16, ucp);
  gemm_qkv<<<dim3(1152), 256, 0, stream>>>(xq16, xk16, xv16, wq16, wk16, wv16,
                                           q_s, k_s, vT, ucp);
  attn_kernel<<<dim3(768), 256, 0, stream>>>(q_s, k_s, vT, ao);
  gemm_out<<<dim3(768), 256, 0, stream>>>(ao, wp16, (float*)d_out, bp);
}